// Round 1
// baseline (4831.836 us; speedup 1.0000x reference)
//
#include <hip/hip_runtime.h>

// ---------------------------------------------------------------------------
// RNN (LSTM) + CRF loss on MI355X.
// Pipeline:
//   1. build_wcat / build_wout : f32 -> bf16 transposed weight copies
//   2. embed_kernel            : x[t][b][e] = word_emb[wx] + mean_l char_emb[cx]
//   3. zero_state              : hs[0]=0 (bf16), c=0 (f32)
//   4. lstm_step_kernel x256   : z = [x_t|h_{t-1}] @ WcatT (MFMA bf16) + b;
//                                gates f32; h->bf16 to hs[t+1]; c stays f32
//   5. em_gemm                 : em[t][b][k] = (hs[t+1]@Wout + bout)*mask (MFMA)
//   6. crf_kernel              : per-b CRF forward (LDS trans) + gold + out
// ---------------------------------------------------------------------------

typedef float f32x4 __attribute__((ext_vector_type(4)));
typedef __bf16 bf16x8 __attribute__((ext_vector_type(8)));

#define T_LEN 256
#define BB    64
#define EE    256
#define HH    512
#define KK    128
#define KCAT  768   // E + H

static __device__ inline unsigned short f2bf(float f) {
  union { float f; unsigned u; } v; v.f = f;
  unsigned r = v.u + 0x7FFF + ((v.u >> 16) & 1);   // round-nearest-even
  return (unsigned short)(r >> 16);
}
static __device__ inline float bf2f(unsigned short u) {
  union { unsigned u; float f; } v; v.u = ((unsigned)u) << 16;
  return v.f;
}

// --- 1. weight conversion --------------------------------------------------
__global__ void build_wcat(const float* __restrict__ Wi, const float* __restrict__ Wh,
                           unsigned short* __restrict__ WcatT) {
  int idx = blockIdx.x * 256 + threadIdx.x;          // over 768*2048
  if (idx >= KCAT * 2048) return;
  int k = idx >> 11, c = idx & 2047;
  float v = (k < EE) ? Wi[k * 2048 + c] : Wh[(k - EE) * 2048 + c];
  WcatT[(size_t)c * KCAT + k] = f2bf(v);
}

__global__ void build_wout(const float* __restrict__ Wout, unsigned short* __restrict__ WoutT) {
  int idx = blockIdx.x * 256 + threadIdx.x;          // over 512*128
  if (idx >= HH * KK) return;
  int k = idx >> 7, n = idx & 127;
  WoutT[n * HH + k] = f2bf(Wout[k * KK + n]);
}

// --- 2. embedding ----------------------------------------------------------
__global__ __launch_bounds__(256) void embed_kernel(
    const int* __restrict__ wx, const int* __restrict__ cx,
    const float* __restrict__ we, const float* __restrict__ ce,
    unsigned short* __restrict__ x) {
  int bid = blockIdx.x;             // t*64 + b
  int t = bid >> 6, b = bid & 63;
  int e = threadIdx.x;              // 0..255
  int w = wx[b * T_LEN + t];
  float v = we[(size_t)w * EE + e];
  const int* cp = cx + ((size_t)(b * T_LEN + t)) * 8;
  float s = 0.f;
#pragma unroll
  for (int l = 0; l < 8; ++l) s += ce[(size_t)cp[l] * EE + e];
  v += s * 0.125f;
  x[(size_t)bid * EE + e] = f2bf(v);
}

// --- 3. zero init ----------------------------------------------------------
__global__ void zero_state(unsigned short* __restrict__ hs, float* __restrict__ c) {
  int idx = blockIdx.x * 256 + threadIdx.x;          // 64*512 = 32768
  hs[idx] = 0;      // bf16 zero
  c[idx] = 0.f;
}

// --- 4. one LSTM step ------------------------------------------------------
// grid 32 blocks (u-slice of 16) x 256 threads (wave = gate).
__global__ __launch_bounds__(256) void lstm_step_kernel(
    const unsigned short* __restrict__ x,     // [T][64][256] bf16
    unsigned short* __restrict__ hs,          // [T+1][64][512] bf16
    float* __restrict__ c,                    // [64][512]
    const unsigned short* __restrict__ WcatT, // [2048][768] bf16
    const float* __restrict__ bias,           // [2048]
    const int* __restrict__ wx,               // [64][256]
    int t) {
  __shared__ float zlds[4][BB][16];           // [gate][b][u] 16KB
  int wave = threadIdx.x >> 6;                // gate
  int lane = threadIdx.x & 63;
  int u0 = blockIdx.x * 16;
  int arow = lane & 15;
  int kgrp = (lane >> 4) * 8;

  const unsigned short* xt = x + (size_t)t * BB * EE;
  const unsigned short* hp = hs + (size_t)t * BB * HH;
  int col = wave * HH + u0 + arow;            // global z column for this lane
  const unsigned short* Bcol = WcatT + (size_t)col * KCAT + kgrp;

  f32x4 acc[4];
#pragma unroll
  for (int mt = 0; mt < 4; ++mt) acc[mt] = (f32x4){0.f, 0.f, 0.f, 0.f};

  // K part 1: x (k in [0,256))
#pragma unroll
  for (int ks = 0; ks < 8; ++ks) {
    bf16x8 bf = *(const bf16x8*)(Bcol + ks * 32);
    int ko = ks * 32 + kgrp;
#pragma unroll
    for (int mt = 0; mt < 4; ++mt) {
      int b = mt * 16 + arow;
      bf16x8 af = *(const bf16x8*)(xt + b * EE + ko);
      acc[mt] = __builtin_amdgcn_mfma_f32_16x16x32_bf16(af, bf, acc[mt], 0, 0, 0);
    }
  }
  // K part 2: h (k in [256,768))
#pragma unroll
  for (int ks = 8; ks < 24; ++ks) {
    bf16x8 bf = *(const bf16x8*)(Bcol + ks * 32);
    int ko = ks * 32 + kgrp - EE;
#pragma unroll
    for (int mt = 0; mt < 4; ++mt) {
      int b = mt * 16 + arow;
      bf16x8 af = *(const bf16x8*)(hp + b * HH + ko);
      acc[mt] = __builtin_amdgcn_mfma_f32_16x16x32_bf16(af, bf, acc[mt], 0, 0, 0);
    }
  }

  float bc = bias[col];
#pragma unroll
  for (int mt = 0; mt < 4; ++mt) {
#pragma unroll
    for (int r = 0; r < 4; ++r) {
      int b = mt * 16 + (lane >> 4) * 4 + r;
      zlds[wave][b][arow] = acc[mt][r] + bc;
    }
  }
  __syncthreads();

  // pointwise gates: 1024 (b,u) pairs over 256 threads
#pragma unroll
  for (int r = 0; r < 4; ++r) {
    int idx = r * 256 + threadIdx.x;
    int b = idx >> 4, ul = idx & 15;
    float zi = zlds[0][b][ul], zf = zlds[1][b][ul];
    float zg = zlds[2][b][ul], zo = zlds[3][b][ul];
    float ig = 1.f / (1.f + __expf(-zi));
    float fg = 1.f / (1.f + __expf(-zf));
    float og = 1.f / (1.f + __expf(-zo));
    float gg = tanhf(zg);
    int cidx = b * HH + u0 + ul;
    float cold = c[cidx];
    float cnew = fg * cold + ig * gg;
    float hnew = og * tanhf(cnew);
    bool m = wx[b * T_LEN + t] > 0;
    float hold = bf2f(hp[cidx]);
    c[cidx] = m ? cnew : cold;
    hs[(size_t)(t + 1) * BB * HH + cidx] = f2bf(m ? hnew : hold);
  }
}

// --- 5. emissions GEMM -----------------------------------------------------
// em[r=t*64+b][n] = (hs[r+64 rows][..] @ Wout + bout[n]) * mask. grid 2048x256.
__global__ __launch_bounds__(256) void em_gemm(
    const unsigned short* __restrict__ hs,    // A base = hs + 64*512
    const unsigned short* __restrict__ WoutT, // [128][512] bf16
    const float* __restrict__ bout,
    const int* __restrict__ wx,
    float* __restrict__ em) {                 // [16384][128]
  int mg = blockIdx.x >> 3;                   // 0..255 (64 rows each)
  int nt = blockIdx.x & 7;                    // n-tile
  int wave = threadIdx.x >> 6, lane = threadIdx.x & 63;
  int arow = lane & 15, kgrp = (lane >> 4) * 8;
  int rbase = (mg * 4 + wave) * 16;
  const unsigned short* A = hs + (size_t)BB * HH + (size_t)(rbase + arow) * HH + kgrp;
  const unsigned short* B = WoutT + (size_t)(nt * 16 + arow) * HH + kgrp;
  f32x4 acc = (f32x4){0.f, 0.f, 0.f, 0.f};
#pragma unroll
  for (int ks = 0; ks < 16; ++ks) {
    bf16x8 a = *(const bf16x8*)(A + ks * 32);
    bf16x8 bf = *(const bf16x8*)(B + ks * 32);
    acc = __builtin_amdgcn_mfma_f32_16x16x32_bf16(a, bf, acc, 0, 0, 0);
  }
  int n = nt * 16 + arow;
  float bo = bout[n];
#pragma unroll
  for (int r = 0; r < 4; ++r) {
    int row = rbase + (lane >> 4) * 4 + r;    // t*64 + b
    int t = row >> 6, b = row & 63;
    float v = (acc[r] + bo) * ((wx[b * T_LEN + t] > 0) ? 1.f : 0.f);
    em[(size_t)row * KK + n] = v;
  }
}

// --- 6. CRF forward + gold -------------------------------------------------
// one block per b, 256 threads (thread = (k, j-half)), trans LDS-resident.
__global__ __launch_bounds__(256) void crf_kernel(
    const float* __restrict__ em,             // [256][64][128]
    const float* __restrict__ trans,          // [128][128]
    const int* __restrict__ wx,
    const int* __restrict__ y,                // [64][257]
    float* __restrict__ out) {
  int b = blockIdx.x;
  __shared__ float tl[KK][129];
  __shared__ float sc[KK];
  __shared__ float red[256];
  __shared__ float red2[256];
  int tid = threadIdx.x;
  for (int i = tid; i < KK * KK; i += 256) tl[i >> 7][i & 127] = trans[i];
  if (tid < KK) sc[tid] = (tid == 1) ? 0.f : -10000.f;
  __syncthreads();

  int k = tid & 127;
  int half = tid >> 7;
  int j0 = half * 64;

  for (int t = 0; t < T_LEN; ++t) {
    if (wx[b * T_LEN + t] <= 0) continue;     // block-uniform
    float mx = -1e30f;
    for (int j = 0; j < 64; ++j) {
      float v = sc[j0 + j] + tl[k][j0 + j];
      mx = fmaxf(mx, v);
    }
    float s = 0.f;
    for (int j = 0; j < 64; ++j) {
      float v = sc[j0 + j] + tl[k][j0 + j];
      s += __expf(v - mx);
    }
    red[tid] = mx; red2[tid] = s;
    __syncthreads();
    float mx2 = red[tid ^ 128], s2 = red2[tid ^ 128];
    float M = fmaxf(mx, mx2);
    float S = s * __expf(mx - M) + s2 * __expf(mx2 - M);
    float ns = em[(size_t)(t * BB + b) * KK + k] + M + __logf(S);
    __syncthreads();
    if (half == 0) sc[k] = ns;
    __syncthreads();
  }

  // gold score
  int tt = tid;                                // one timestep per thread
  int yp = y[b * 257 + tt];
  int yn = y[b * 257 + tt + 1];
  bool mm = wx[b * T_LEN + tt] > 0;
  float term = mm ? (em[(size_t)(tt * BB + b) * KK + yn] + tl[yn][yp]) : 0.f;
  red[tid] = term; red2[tid] = mm ? 1.f : 0.f;
  __syncthreads();
  for (int s = 128; s > 0; s >>= 1) {
    if (tid < s) { red[tid] += red[tid + s]; red2[tid] += red2[tid + s]; }
    __syncthreads();
  }
  float gold = red[0];
  int len = (int)(red2[0] + 0.5f);
  __syncthreads();

  // Z = LSE_k(sc[k] + trans[EOS][k])
  float v = (tid < KK) ? sc[tid] + tl[2][tid] : -3.0e38f;
  red[tid] = v; __syncthreads();
  for (int s = 128; s > 0; s >>= 1) {
    if (tid < s) red[tid] = fmaxf(red[tid], red[tid + s]);
    __syncthreads();
  }
  float mz = red[0]; __syncthreads();
  red[tid] = (tid < KK) ? __expf(v - mz) : 0.f;
  __syncthreads();
  for (int s = 128; s > 0; s >>= 1) {
    if (tid < s) red[tid] += red[tid + s];
    __syncthreads();
  }
  if (tid == 0) {
    float Z = mz + __logf(red[0]);
    int last_tag = y[b * 257 + len];
    out[b] = Z - (gold + tl[2][last_tag]);
  }
}

// ---------------------------------------------------------------------------
extern "C" void kernel_launch(void* const* d_in, const int* in_sizes, int n_in,
                              void* d_out, int out_size, void* d_ws, size_t ws_size,
                              hipStream_t stream) {
  const int*   cx    = (const int*)d_in[0];
  const int*   wx    = (const int*)d_in[1];
  const int*   y     = (const int*)d_in[2];
  const float* ce    = (const float*)d_in[3];
  const float* we    = (const float*)d_in[4];
  const float* Wi    = (const float*)d_in[5];
  const float* Wh    = (const float*)d_in[6];
  const float* bias  = (const float*)d_in[7];
  const float* Wout  = (const float*)d_in[8];
  const float* bout  = (const float*)d_in[9];
  const float* trans = (const float*)d_in[10];
  float* out = (float*)d_out;

  char* ws = (char*)d_ws;
  // ws layout (all 16B aligned), total ~35.3 MB
  unsigned short* WcatT = (unsigned short*)(ws + 0);          // 2048*768*2  = 3,145,728
  unsigned short* WoutT = (unsigned short*)(ws + 3145728);    // 128*512*2   =   131,072
  unsigned short* x     = (unsigned short*)(ws + 3276800);    // 16384*256*2 = 8,388,608
  unsigned short* hs    = (unsigned short*)(ws + 11665408);   // 257*64*512*2= 16,842,752
  float*          c     = (float*)(ws + 28508160);            // 64*512*4    =   131,072
  float*          em    = (float*)(ws + 28639232);            // 16384*128*4 = 8,388,608

  build_wcat<<<(KCAT * 2048 + 255) / 256, 256, 0, stream>>>(Wi, Wh, WcatT);
  build_wout<<<(HH * KK + 255) / 256, 256, 0, stream>>>(Wout, WoutT);
  embed_kernel<<<T_LEN * BB, 256, 0, stream>>>(wx, cx, we, ce, x);
  zero_state<<<128, 256, 0, stream>>>(hs, c);
  for (int t = 0; t < T_LEN; ++t)
    lstm_step_kernel<<<32, 256, 0, stream>>>(x, hs, c, WcatT, bias, wx, t);
  em_gemm<<<2048, 256, 0, stream>>>(hs, WoutT, bout, wx, em);
  crf_kernel<<<BB, 256, 0, stream>>>(em, trans, wx, y, out);
}

// Round 2
// 2652.280 us; speedup vs baseline: 1.8218x; 1.8218x over previous
//
#include <hip/hip_runtime.h>

// ---------------------------------------------------------------------------
// RNN (LSTM) + CRF loss on MI355X — round 2: persistent LSTM kernel.
//   1. build_wcat / build_wout : f32 -> bf16 transposed weight copies
//   2. embed_kernel            : x[t][b][e] = word_emb[wx] + mean_l char_emb[cx]
//   3. zero_bar                : grid-barrier counter = 0
//   4. lstm_persistent (x1)    : 32 blocks, Wcat slice LDS-resident, c/h in
//                                registers, manual grid barrier per timestep
//   5. em_gemm                 : em[t][b][k] = (hs[t+1]@Wout + bout)*mask
//   6. crf_kernel              : per-b CRF forward (LDS trans) + gold + out
// ---------------------------------------------------------------------------

typedef float f32x4 __attribute__((ext_vector_type(4)));
typedef __bf16 bf16x8 __attribute__((ext_vector_type(8)));

#define T_LEN 256
#define BB    64
#define EE    256
#define HH    512
#define KK    128
#define KCAT  768   // E + H
#define NBLK  32
#define WPAD  776   // 768 + 8 : LDS row stride (bank spread for ds_read_b128)

static __device__ inline unsigned short f2bf(float f) {
  union { float f; unsigned u; } v; v.f = f;
  unsigned r = v.u + 0x7FFF + ((v.u >> 16) & 1);   // round-nearest-even
  return (unsigned short)(r >> 16);
}
static __device__ inline float sigm(float x) { return 1.f / (1.f + __expf(-x)); }
static __device__ inline float tanh_fast(float x) {
  return 1.f - 2.f / (1.f + __expf(2.f * x));      // safe at +/-inf
}

// --- 1. weight conversion --------------------------------------------------
__global__ void build_wcat(const float* __restrict__ Wi, const float* __restrict__ Wh,
                           unsigned short* __restrict__ WcatT) {
  int idx = blockIdx.x * 256 + threadIdx.x;          // over 768*2048
  if (idx >= KCAT * 2048) return;
  int k = idx >> 11, c = idx & 2047;
  float v = (k < EE) ? Wi[k * 2048 + c] : Wh[(k - EE) * 2048 + c];
  WcatT[(size_t)c * KCAT + k] = f2bf(v);
}

__global__ void build_wout(const float* __restrict__ Wout, unsigned short* __restrict__ WoutT) {
  int idx = blockIdx.x * 256 + threadIdx.x;          // over 512*128
  if (idx >= HH * KK) return;
  int k = idx >> 7, n = idx & 127;
  WoutT[n * HH + k] = f2bf(Wout[k * KK + n]);
}

// --- 2. embedding ----------------------------------------------------------
__global__ __launch_bounds__(256) void embed_kernel(
    const int* __restrict__ wx, const int* __restrict__ cx,
    const float* __restrict__ we, const float* __restrict__ ce,
    unsigned short* __restrict__ x) {
  int bid = blockIdx.x;             // t*64 + b
  int t = bid >> 6, b = bid & 63;
  int e = threadIdx.x;              // 0..255
  int w = wx[b * T_LEN + t];
  float v = we[(size_t)w * EE + e];
  const int* cp = cx + ((size_t)(b * T_LEN + t)) * 8;
  float s = 0.f;
#pragma unroll
  for (int l = 0; l < 8; ++l) s += ce[(size_t)cp[l] * EE + e];
  v += s * 0.125f;
  x[(size_t)bid * EE + e] = f2bf(v);
}

// --- 3. barrier counter reset ---------------------------------------------
__global__ void zero_bar(unsigned int* __restrict__ bar) { bar[0] = 0u; }

// --- grid barrier (32 co-resident blocks, cross-XCD safe) -------------------
static __device__ inline void grid_bar(unsigned int* bar, unsigned int target) {
  __syncthreads();                       // all waves' stores issued (vmcnt drained)
  if (threadIdx.x == 0) {
    __threadfence();                     // agent release: L2 writeback
    __hip_atomic_fetch_add(bar, 1u, __ATOMIC_RELAXED, __HIP_MEMORY_SCOPE_AGENT);
    while (__hip_atomic_load(bar, __ATOMIC_RELAXED, __HIP_MEMORY_SCOPE_AGENT) < target)
      __builtin_amdgcn_s_sleep(1);
    __threadfence();                     // agent acquire: cache invalidate
  }
  __syncthreads();
}

// --- 4. persistent LSTM ----------------------------------------------------
// 32 blocks x 512 threads. Block owns u-slice [u0, u0+16) -> 64 z-columns
// (4 gates x 16 u). Wcat slice LDS-resident; c,h state in registers.
__global__ __launch_bounds__(512) void lstm_persistent(
    const unsigned short* __restrict__ x,     // [T][64][256] bf16
    unsigned short* __restrict__ hs,          // [T+1][64][512] bf16
    const unsigned short* __restrict__ WcatT, // [2048][768] bf16
    const float* __restrict__ bias,           // [2048]
    const int* __restrict__ wx,               // [64][256]
    unsigned int* __restrict__ bar) {
  __shared__ unsigned short wlds[64][WPAD];   // 99.3 KB
  __shared__ float zlds[4][BB][17];           // 17.4 KB
  int tid = threadIdx.x;
  int u0 = blockIdx.x * 16;

  // load Wcat slice: local col c -> global col (c>>4)*512 + u0 + (c&15)
  for (int i = tid; i < 64 * 96; i += 512) {
    int c = i / 96, ch = i % 96;
    int gcol = (c >> 4) * HH + u0 + (c & 15);
    *(bf16x8*)(&wlds[c][ch * 8]) = *(const bf16x8*)(WcatT + (size_t)gcol * KCAT + ch * 8);
  }
  // zero hs[0] for our u-slice (union over blocks covers all 512 u)
  for (int i = tid; i < BB * 16; i += 512) {
    int b = i >> 4, u = i & 15;
    hs[b * HH + u0 + u] = 0;
  }

  int wave = tid >> 6, lane = tid & 63;
  int m = wave >> 1, nh = wave & 1;           // m-tile 0..3, n-half 0..1
  int arow = lane & 15, kg = (lane >> 4) * 8;

  // loop-invariant B pointers (LDS rows) and bias values
  const unsigned short* bl0 = &wlds[(nh * 2 + 0) * 16 + arow][0];
  const unsigned short* bl1 = &wlds[(nh * 2 + 1) * 16 + arow][0];
  float bv0 = bias[(nh * 2 + 0) * HH + u0 + arow];
  float bv1 = bias[(nh * 2 + 1) * HH + u0 + arow];

  // per-thread gate state: 2 (b,u) pairs
  int p0 = tid * 2, p1 = tid * 2 + 1;
  int b0 = p0 >> 4, uu0 = p0 & 15;
  int b1 = p1 >> 4, uu1 = p1 & 15;
  float c0 = 0.f, c1 = 0.f, h0 = 0.f, h1 = 0.f;

  grid_bar(bar, NBLK);                        // hs[0] visible everywhere

  for (int t = 0; t < T_LEN; ++t) {
    const unsigned short* xt = x + (size_t)t * BB * EE + (size_t)(m * 16 + arow) * EE + kg;
    const unsigned short* hp = hs + (size_t)t * BB * HH + (size_t)(m * 16 + arow) * HH + kg;
    // issue mask loads early
    int mk0 = wx[b0 * T_LEN + t];
    int mk1 = wx[b1 * T_LEN + t];

    f32x4 acc0 = (f32x4){0.f, 0.f, 0.f, 0.f};
    f32x4 acc1 = (f32x4){0.f, 0.f, 0.f, 0.f};
#pragma unroll
    for (int ks = 0; ks < 8; ++ks) {          // x part, k in [0,256)
      bf16x8 a  = *(const bf16x8*)(xt + ks * 32);
      bf16x8 f0 = *(const bf16x8*)(bl0 + ks * 32 + kg);
      bf16x8 f1 = *(const bf16x8*)(bl1 + ks * 32 + kg);
      acc0 = __builtin_amdgcn_mfma_f32_16x16x32_bf16(a, f0, acc0, 0, 0, 0);
      acc1 = __builtin_amdgcn_mfma_f32_16x16x32_bf16(a, f1, acc1, 0, 0, 0);
    }
#pragma unroll
    for (int ks = 0; ks < 16; ++ks) {         // h part, k in [256,768)
      bf16x8 a  = *(const bf16x8*)(hp + ks * 32);
      bf16x8 f0 = *(const bf16x8*)(bl0 + EE + ks * 32 + kg);
      bf16x8 f1 = *(const bf16x8*)(bl1 + EE + ks * 32 + kg);
      acc0 = __builtin_amdgcn_mfma_f32_16x16x32_bf16(a, f0, acc0, 0, 0, 0);
      acc1 = __builtin_amdgcn_mfma_f32_16x16x32_bf16(a, f1, acc1, 0, 0, 0);
    }
#pragma unroll
    for (int r = 0; r < 4; ++r) {
      int b = m * 16 + (lane >> 4) * 4 + r;
      zlds[nh * 2 + 0][b][arow] = acc0[r] + bv0;
      zlds[nh * 2 + 1][b][arow] = acc1[r] + bv1;
    }
    __syncthreads();

    // gates: thread handles (b0,uu0) and (b1,uu1)
    {
      float zi = zlds[0][b0][uu0], zf = zlds[1][b0][uu0];
      float zg = zlds[2][b0][uu0], zo = zlds[3][b0][uu0];
      float cn = sigm(zf) * c0 + sigm(zi) * tanh_fast(zg);
      float hn = sigm(zo) * tanh_fast(cn);
      if (mk0 > 0) { c0 = cn; h0 = hn; }
      hs[(size_t)(t + 1) * BB * HH + b0 * HH + u0 + uu0] = f2bf(h0);
    }
    {
      float zi = zlds[0][b1][uu1], zf = zlds[1][b1][uu1];
      float zg = zlds[2][b1][uu1], zo = zlds[3][b1][uu1];
      float cn = sigm(zf) * c1 + sigm(zi) * tanh_fast(zg);
      float hn = sigm(zo) * tanh_fast(cn);
      if (mk1 > 0) { c1 = cn; h1 = hn; }
      hs[(size_t)(t + 1) * BB * HH + b1 * HH + u0 + uu1] = f2bf(h1);
    }
    grid_bar(bar, (unsigned)NBLK * (t + 2));  // hs[t+1] visible; zlds safe to reuse
  }
}

// --- 5. emissions GEMM -----------------------------------------------------
__global__ __launch_bounds__(256) void em_gemm(
    const unsigned short* __restrict__ hs,    // A base = hs + 64*512
    const unsigned short* __restrict__ WoutT, // [128][512] bf16
    const float* __restrict__ bout,
    const int* __restrict__ wx,
    float* __restrict__ em) {                 // [16384][128]
  int mg = blockIdx.x >> 3;                   // 0..255 (64 rows each)
  int nt = blockIdx.x & 7;                    // n-tile
  int wave = threadIdx.x >> 6, lane = threadIdx.x & 63;
  int arow = lane & 15, kgrp = (lane >> 4) * 8;
  int rbase = (mg * 4 + wave) * 16;
  const unsigned short* A = hs + (size_t)BB * HH + (size_t)(rbase + arow) * HH + kgrp;
  const unsigned short* B = WoutT + (size_t)(nt * 16 + arow) * HH + kgrp;
  f32x4 acc = (f32x4){0.f, 0.f, 0.f, 0.f};
#pragma unroll
  for (int ks = 0; ks < 16; ++ks) {
    bf16x8 a = *(const bf16x8*)(A + ks * 32);
    bf16x8 bf = *(const bf16x8*)(B + ks * 32);
    acc = __builtin_amdgcn_mfma_f32_16x16x32_bf16(a, bf, acc, 0, 0, 0);
  }
  int n = nt * 16 + arow;
  float bo = bout[n];
#pragma unroll
  for (int r = 0; r < 4; ++r) {
    int row = rbase + (lane >> 4) * 4 + r;    // t*64 + b
    int t = row >> 6, b = row & 63;
    float v = (acc[r] + bo) * ((wx[b * T_LEN + t] > 0) ? 1.f : 0.f);
    em[(size_t)row * KK + n] = v;
  }
}

// --- 6. CRF forward + gold -------------------------------------------------
__global__ __launch_bounds__(256) void crf_kernel(
    const float* __restrict__ em,             // [256][64][128]
    const float* __restrict__ trans,          // [128][128]
    const int* __restrict__ wx,
    const int* __restrict__ y,                // [64][257]
    float* __restrict__ out) {
  int b = blockIdx.x;
  __shared__ float tl[KK][129];
  __shared__ float sc[KK];
  __shared__ float red[256];
  __shared__ float red2[256];
  int tid = threadIdx.x;
  for (int i = tid; i < KK * KK; i += 256) tl[i >> 7][i & 127] = trans[i];
  if (tid < KK) sc[tid] = (tid == 1) ? 0.f : -10000.f;
  __syncthreads();

  int k = tid & 127;
  int half = tid >> 7;
  int j0 = half * 64;

  for (int t = 0; t < T_LEN; ++t) {
    if (wx[b * T_LEN + t] <= 0) continue;     // block-uniform
    float mx = -1e30f;
    for (int j = 0; j < 64; ++j) {
      float v = sc[j0 + j] + tl[k][j0 + j];
      mx = fmaxf(mx, v);
    }
    float s = 0.f;
    for (int j = 0; j < 64; ++j) {
      float v = sc[j0 + j] + tl[k][j0 + j];
      s += __expf(v - mx);
    }
    red[tid] = mx; red2[tid] = s;
    __syncthreads();
    float mx2 = red[tid ^ 128], s2 = red2[tid ^ 128];
    float M = fmaxf(mx, mx2);
    float S = s * __expf(mx - M) + s2 * __expf(mx2 - M);
    float ns = em[(size_t)(t * BB + b) * KK + k] + M + __logf(S);
    __syncthreads();
    if (half == 0) sc[k] = ns;
    __syncthreads();
  }

  // gold score
  int tt = tid;
  int yp = y[b * 257 + tt];
  int yn = y[b * 257 + tt + 1];
  bool mm = wx[b * T_LEN + tt] > 0;
  float term = mm ? (em[(size_t)(tt * BB + b) * KK + yn] + tl[yn][yp]) : 0.f;
  red[tid] = term; red2[tid] = mm ? 1.f : 0.f;
  __syncthreads();
  for (int s = 128; s > 0; s >>= 1) {
    if (tid < s) { red[tid] += red[tid + s]; red2[tid] += red2[tid + s]; }
    __syncthreads();
  }
  float gold = red[0];
  int len = (int)(red2[0] + 0.5f);
  __syncthreads();

  // Z = LSE_k(sc[k] + trans[EOS][k])
  float v = (tid < KK) ? sc[tid] + tl[2][tid] : -3.0e38f;
  red[tid] = v; __syncthreads();
  for (int s = 128; s > 0; s >>= 1) {
    if (tid < s) red[tid] = fmaxf(red[tid], red[tid + s]);
    __syncthreads();
  }
  float mz = red[0]; __syncthreads();
  red[tid] = (tid < KK) ? __expf(v - mz) : 0.f;
  __syncthreads();
  for (int s = 128; s > 0; s >>= 1) {
    if (tid < s) red[tid] += red[tid + s];
    __syncthreads();
  }
  if (tid == 0) {
    float Z = mz + __logf(red[0]);
    int last_tag = y[b * 257 + len];
    out[b] = Z - (gold + tl[2][last_tag]);
  }
}

// ---------------------------------------------------------------------------
extern "C" void kernel_launch(void* const* d_in, const int* in_sizes, int n_in,
                              void* d_out, int out_size, void* d_ws, size_t ws_size,
                              hipStream_t stream) {
  const int*   cx    = (const int*)d_in[0];
  const int*   wx    = (const int*)d_in[1];
  const int*   y     = (const int*)d_in[2];
  const float* ce    = (const float*)d_in[3];
  const float* we    = (const float*)d_in[4];
  const float* Wi    = (const float*)d_in[5];
  const float* Wh    = (const float*)d_in[6];
  const float* bias  = (const float*)d_in[7];
  const float* Wout  = (const float*)d_in[8];
  const float* bout  = (const float*)d_in[9];
  const float* trans = (const float*)d_in[10];
  float* out = (float*)d_out;

  char* ws = (char*)d_ws;
  // ws layout (16B aligned), total ~35.3 MB
  unsigned short* WcatT = (unsigned short*)(ws + 0);          // 3,145,728
  unsigned short* WoutT = (unsigned short*)(ws + 3145728);    //   131,072
  unsigned short* x     = (unsigned short*)(ws + 3276800);    // 8,388,608
  unsigned short* hs    = (unsigned short*)(ws + 11665408);   // 16,842,752
  unsigned int*   bar   = (unsigned int*)(ws + 28508160);     //         4
  float*          em    = (float*)(ws + 28639232);            // 8,388,608

  build_wcat<<<(KCAT * 2048 + 255) / 256, 256, 0, stream>>>(Wi, Wh, WcatT);
  build_wout<<<(HH * KK + 255) / 256, 256, 0, stream>>>(Wout, WoutT);
  embed_kernel<<<T_LEN * BB, 256, 0, stream>>>(wx, cx, we, ce, x);
  zero_bar<<<1, 1, 0, stream>>>(bar);
  lstm_persistent<<<NBLK, 512, 0, stream>>>(x, hs, WcatT, bias, wx, bar);
  em_gemm<<<2048, 256, 0, stream>>>(hs, WoutT, bout, wx, em);
  crf_kernel<<<BB, 256, 0, stream>>>(em, trans, wx, y, out);
}

// Round 3
// 2169.784 us; speedup vs baseline: 2.2269x; 1.2224x over previous
//
#include <hip/hip_runtime.h>

// ---------------------------------------------------------------------------
// RNN (LSTM) + CRF loss on MI355X — round 3.
// LSTM: persistent kernel, fence-free LLC-coherent h exchange, h-part weights
// in registers, fragment-ordered LDS (zero bank conflicts on weight reads).
// ---------------------------------------------------------------------------

typedef float f32x4 __attribute__((ext_vector_type(4)));
typedef __bf16 bf16x8 __attribute__((ext_vector_type(8)));

#define T_LEN 256
#define BB    64
#define EE    256
#define HH    512
#define KK    128
#define KCAT  768   // E + H
#define NBLK  32

static __device__ inline unsigned short f2bf(float f) {
  union { float f; unsigned u; } v; v.f = f;
  unsigned r = v.u + 0x7FFF + ((v.u >> 16) & 1);   // round-nearest-even
  return (unsigned short)(r >> 16);
}
static __device__ inline float sigm(float x) { return 1.f / (1.f + __expf(-x)); }
static __device__ inline float tanh_fast(float x) {
  return 1.f - 2.f / (1.f + __expf(2.f * x));      // safe at +/-inf
}

// --- 1. weight conversion (LDS tile transpose, coalesced both sides) -------
__global__ __launch_bounds__(256) void build_wcat(
    const float* __restrict__ Wi, const float* __restrict__ Wh,
    unsigned short* __restrict__ WcatT) {
  __shared__ float tile[64][65];
  int ct = blockIdx.x & 31, kt = blockIdx.x >> 5;    // 32 c-tiles x 12 k-tiles
  int tc = threadIdx.x & 63, tr = threadIdx.x >> 6;
  int c0 = ct * 64, k0 = kt * 64;
#pragma unroll
  for (int i = 0; i < 16; ++i) {
    int r = tr * 16 + i, k = k0 + r;
    float v = (k < EE) ? Wi[(size_t)k * 2048 + c0 + tc]
                       : Wh[(size_t)(k - EE) * 2048 + c0 + tc];
    tile[r][tc] = v;
  }
  __syncthreads();
#pragma unroll
  for (int i = 0; i < 16; ++i) {
    int cL = tr * 16 + i;
    WcatT[(size_t)(c0 + cL) * KCAT + k0 + tc] = f2bf(tile[tc][cL]);
  }
}

__global__ __launch_bounds__(256) void build_wout(
    const float* __restrict__ Wout, unsigned short* __restrict__ WoutT) {
  __shared__ float tile[64][65];
  int ct = blockIdx.x & 1, kt = blockIdx.x >> 1;     // 2 c-tiles x 8 k-tiles
  int tc = threadIdx.x & 63, tr = threadIdx.x >> 6;
  int c0 = ct * 64, k0 = kt * 64;
#pragma unroll
  for (int i = 0; i < 16; ++i) {
    int r = tr * 16 + i;
    tile[r][tc] = Wout[(size_t)(k0 + r) * KK + c0 + tc];
  }
  __syncthreads();
#pragma unroll
  for (int i = 0; i < 16; ++i) {
    int cL = tr * 16 + i;
    WoutT[(size_t)(c0 + cL) * HH + k0 + tc] = f2bf(tile[tc][cL]);
  }
}

// --- 2. embedding ----------------------------------------------------------
__global__ __launch_bounds__(256) void embed_kernel(
    const int* __restrict__ wx, const int* __restrict__ cx,
    const float* __restrict__ we, const float* __restrict__ ce,
    unsigned short* __restrict__ x) {
  int bid = blockIdx.x;             // t*64 + b
  int t = bid >> 6, b = bid & 63;
  int e = threadIdx.x;              // 0..255
  int w = wx[b * T_LEN + t];
  float v = we[(size_t)w * EE + e];
  const int* cp = cx + ((size_t)(b * T_LEN + t)) * 8;
  float s = 0.f;
#pragma unroll
  for (int l = 0; l < 8; ++l) s += ce[(size_t)cp[l] * EE + e];
  v += s * 0.125f;
  x[(size_t)bid * EE + e] = f2bf(v);
}

// --- 3. barrier counter reset ---------------------------------------------
__global__ void zero_bar(unsigned int* __restrict__ bar) { bar[0] = 0u; }

// --- 4. persistent LSTM ----------------------------------------------------
// 32 blocks x 512 threads. Block owns u-slice [u0,u0+16) -> 64 z-cols.
// x-part weights in fragment-ordered LDS; h-part weights in registers.
// h exchange: relaxed agent atomic stores (write-through to LLC) + sc0/sc1
// bypass loads; barrier = vmcnt drain + atomicAdd + one-thread spin.
__global__ __launch_bounds__(512, 2) void lstm_persistent(
    const unsigned short* __restrict__ x,     // [T][64][256] bf16
    unsigned short* __restrict__ hs,          // [T+1][64][512] bf16
    const unsigned short* __restrict__ WcatT, // [2048][768] bf16
    const float* __restrict__ bias,           // [2048]
    const int* __restrict__ wx,               // [64][256]
    unsigned int* __restrict__ bar) {
  __shared__ unsigned short wlds[4 * 24 * 64 * 8];   // 96 KB, fragment order
  __shared__ float zlds[4][BB][17];                  // 17.4 KB
  const int tid = threadIdx.x;
  const int u0 = blockIdx.x * 16;

  // stage weights in MFMA-fragment order: frag (g, ks, lane) =
  // WcatT[(g*512 + u0 + (lane&15)) * 768 + ks*32 + (lane>>4)*8 .. +8]
  for (int i = tid; i < 4 * 24 * 64; i += 512) {
    int lane = i & 63;
    int ks = (i >> 6) % 24;
    int g = i / (24 * 64);
    int ar = lane & 15, kgi = lane >> 4;
    int gcol = g * HH + u0 + ar;
    *(bf16x8*)(&wlds[(size_t)i * 8]) =
        *(const bf16x8*)(WcatT + (size_t)gcol * KCAT + ks * 32 + kgi * 8);
  }
  __syncthreads();

  const int wave = tid >> 6, lane = tid & 63;
  const int m = wave >> 1, nh = wave & 1;     // m-tile 0..3, gate-pair 0..1
  const int arow = lane & 15, kg = (lane >> 4) * 8;
  const int g0 = nh * 2, g1 = g0 + 1;
  const unsigned short* wb0 = wlds + ((size_t)(g0 * 24) * 64 + lane) * 8;
  const unsigned short* wb1 = wlds + ((size_t)(g1 * 24) * 64 + lane) * 8;
  const float bv0 = bias[g0 * HH + u0 + arow];
  const float bv1 = bias[g1 * HH + u0 + arow];

  // h-part weights -> registers (32 fragments = 128 VGPRs, loop-invariant)
  bf16x8 wh0[16], wh1[16];
#pragma unroll
  for (int ks = 0; ks < 16; ++ks) {
    wh0[ks] = *(const bf16x8*)(wb0 + (8 + ks) * 512);
    wh1[ks] = *(const bf16x8*)(wb1 + (8 + ks) * 512);
  }

  // per-thread gate state: pair (b0, uu0), (b0, uu0+1)
  const int b0 = tid >> 3;
  const int uu0 = (2 * tid) & 15;             // even
  float c0 = 0.f, c1 = 0.f, h0 = 0.f, h1 = 0.f;

  for (int t = 0; t < T_LEN; ++t) {
    const int mk = wx[b0 * T_LEN + t];
    const unsigned short* xt = x + ((size_t)t * BB + m * 16 + arow) * EE + kg;
    f32x4 acc0 = (f32x4){0.f, 0.f, 0.f, 0.f};
    f32x4 acc1 = (f32x4){0.f, 0.f, 0.f, 0.f};

    // x-part: no h[t] dependency -> runs while other blocks finish step t-1
#pragma unroll
    for (int ks = 0; ks < 8; ++ks) {
      bf16x8 a  = *(const bf16x8*)(xt + ks * 32);
      bf16x8 f0 = *(const bf16x8*)(wb0 + ks * 512);
      bf16x8 f1 = *(const bf16x8*)(wb1 + ks * 512);
      acc0 = __builtin_amdgcn_mfma_f32_16x16x32_bf16(a, f0, acc0, 0, 0, 0);
      acc1 = __builtin_amdgcn_mfma_f32_16x16x32_bf16(a, f1, acc1, 0, 0, 0);
    }

    if (t > 0) {
      if (tid == 0) {
        const unsigned tgt = (unsigned)(NBLK * t);
        while (__hip_atomic_load(bar, __ATOMIC_RELAXED, __HIP_MEMORY_SCOPE_AGENT) < tgt)
          __builtin_amdgcn_s_sleep(1);
      }
      __syncthreads();
      // h[t] fragments: LLC-coherent loads (bypass stale L1/L2)
      const unsigned short* hp = hs + ((size_t)t * BB + m * 16 + arow) * HH + kg;
      bf16x8 hf[16];
#pragma unroll
      for (int ks = 0; ks < 16; ++ks)
        asm volatile("global_load_dwordx4 %0, %1, off sc0 sc1"
                     : "=v"(hf[ks]) : "v"(hp + ks * 32) : "memory");
      asm volatile("s_waitcnt vmcnt(0)" ::: "memory");
      __builtin_amdgcn_sched_barrier(0);
#pragma unroll
      for (int ks = 0; ks < 16; ++ks) {
        acc0 = __builtin_amdgcn_mfma_f32_16x16x32_bf16(hf[ks], wh0[ks], acc0, 0, 0, 0);
        acc1 = __builtin_amdgcn_mfma_f32_16x16x32_bf16(hf[ks], wh1[ks], acc1, 0, 0, 0);
      }
    }

#pragma unroll
    for (int r = 0; r < 4; ++r) {
      const int bb = m * 16 + (lane >> 4) * 4 + r;
      zlds[g0][bb][arow] = acc0[r] + bv0;
      zlds[g1][bb][arow] = acc1[r] + bv1;
    }
    __syncthreads();

    // gates for the two owned (b,u) pairs
    {
      float zi = zlds[0][b0][uu0], zf = zlds[1][b0][uu0];
      float zg = zlds[2][b0][uu0], zo = zlds[3][b0][uu0];
      float cn = sigm(zf) * c0 + sigm(zi) * tanh_fast(zg);
      float hn = sigm(zo) * tanh_fast(cn);
      if (mk > 0) { c0 = cn; h0 = hn; }
    }
    {
      float zi = zlds[0][b0][uu0 + 1], zf = zlds[1][b0][uu0 + 1];
      float zg = zlds[2][b0][uu0 + 1], zo = zlds[3][b0][uu0 + 1];
      float cn = sigm(zf) * c1 + sigm(zi) * tanh_fast(zg);
      float hn = sigm(zo) * tanh_fast(cn);
      if (mk > 0) { c1 = cn; h1 = hn; }
    }
    // publish h[t+1]: packed write-through to LLC
    unsigned pk = (unsigned)f2bf(h0) | ((unsigned)f2bf(h1) << 16);
    unsigned* hw = (unsigned*)(hs + (size_t)(t + 1) * BB * HH + b0 * HH + u0 + uu0);
    __hip_atomic_store(hw, pk, __ATOMIC_RELAXED, __HIP_MEMORY_SCOPE_AGENT);
    __syncthreads();                            // drains all waves' stores (vmcnt)
    if (tid == 0)
      __hip_atomic_fetch_add(bar, 1u, __ATOMIC_RELAXED, __HIP_MEMORY_SCOPE_AGENT);
  }
}

// --- 5. emissions GEMM: 256 blocks x 512 thr, 64 rows x 128 cols/block -----
__global__ __launch_bounds__(512) void em_gemm(
    const unsigned short* __restrict__ hs,    // A base = hs + 64*512
    const unsigned short* __restrict__ WoutT, // [128][512] bf16
    const float* __restrict__ bout,
    const int* __restrict__ wx,
    float* __restrict__ em) {                 // [16384][128]
  int mg = blockIdx.x;                        // 0..255
  int wave = threadIdx.x >> 6, lane = threadIdx.x & 63;
  int m = wave >> 1, nh = wave & 1;
  int arow = lane & 15, kg = (lane >> 4) * 8;
  int rbase = mg * 64 + m * 16;
  const unsigned short* A = hs + (size_t)BB * HH + (size_t)(rbase + arow) * HH + kg;
  f32x4 acc[4];
#pragma unroll
  for (int nt = 0; nt < 4; ++nt) acc[nt] = (f32x4){0.f, 0.f, 0.f, 0.f};
#pragma unroll
  for (int ks = 0; ks < 16; ++ks) {
    bf16x8 a = *(const bf16x8*)(A + ks * 32);
#pragma unroll
    for (int nt = 0; nt < 4; ++nt) {
      const unsigned short* Bp =
          WoutT + (size_t)(nh * 64 + nt * 16 + arow) * HH + kg + ks * 32;
      acc[nt] = __builtin_amdgcn_mfma_f32_16x16x32_bf16(a, *(const bf16x8*)Bp, acc[nt], 0, 0, 0);
    }
  }
#pragma unroll
  for (int nt = 0; nt < 4; ++nt) {
    int n = nh * 64 + nt * 16 + arow;
    float bo = bout[n];
#pragma unroll
    for (int r = 0; r < 4; ++r) {
      int row = rbase + (lane >> 4) * 4 + r;  // t*64 + b
      int t = row >> 6, b = row & 63;
      float v = (acc[nt][r] + bo) * ((wx[b * T_LEN + t] > 0) ? 1.f : 0.f);
      em[(size_t)row * KK + n] = v;
    }
  }
}

// --- 6. CRF forward + gold (512 threads: k x j-quarter) ---------------------
__global__ __launch_bounds__(512) void crf_kernel(
    const float* __restrict__ em,             // [256][64][128]
    const float* __restrict__ trans,          // [128][128]
    const int* __restrict__ wx,
    const int* __restrict__ y,                // [64][257]
    float* __restrict__ out) {
  int b = blockIdx.x;
  __shared__ float tl[KK][129];
  __shared__ float sc[KK];
  __shared__ float red[512];
  __shared__ float red2[512];
  int tid = threadIdx.x;
  for (int i = tid; i < KK * KK; i += 512) tl[i >> 7][i & 127] = trans[i];
  if (tid < KK) sc[tid] = (tid == 1) ? 0.f : -10000.f;
  __syncthreads();

  int k = tid & 127, q = tid >> 7, j0 = q * 32;

  for (int t = 0; t < T_LEN; ++t) {
    if (wx[b * T_LEN + t] <= 0) continue;     // block-uniform
    float mx = -1e30f;
#pragma unroll
    for (int j = 0; j < 32; ++j) mx = fmaxf(mx, sc[j0 + j] + tl[k][j0 + j]);
    float s = 0.f;
#pragma unroll
    for (int j = 0; j < 32; ++j) s += __expf(sc[j0 + j] + tl[k][j0 + j] - mx);
    red[tid] = mx; red2[tid] = s;
    __syncthreads();
    if (q == 0) {
      float M = mx, S = s;
#pragma unroll
      for (int qq = 1; qq < 4; ++qq) {
        float m2 = red[qq * 128 + k], s2 = red2[qq * 128 + k];
        float Mn = fmaxf(M, m2);
        S = S * __expf(M - Mn) + s2 * __expf(m2 - Mn);
        M = Mn;
      }
      sc[k] = em[(size_t)(t * BB + b) * KK + k] + M + __logf(S);
    }
    __syncthreads();
  }

  // gold score
  float term = 0.f, cnt = 0.f;
  if (tid < T_LEN) {
    int yp = y[b * 257 + tid], yn = y[b * 257 + tid + 1];
    if (wx[b * T_LEN + tid] > 0) {
      term = em[(size_t)(tid * BB + b) * KK + yn] + tl[yn][yp];
      cnt = 1.f;
    }
  }
  red[tid] = term; red2[tid] = cnt;
  __syncthreads();
  for (int s2 = 256; s2 > 0; s2 >>= 1) {
    if (tid < s2) { red[tid] += red[tid + s2]; red2[tid] += red2[tid + s2]; }
    __syncthreads();
  }
  float gold = red[0];
  int len = (int)(red2[0] + 0.5f);
  __syncthreads();

  // Z = LSE_k(sc[k] + trans[EOS][k])
  float v = (tid < KK) ? sc[tid] + tl[2][tid] : -3.0e38f;
  red[tid] = v;
  __syncthreads();
  for (int s2 = 256; s2 > 0; s2 >>= 1) {
    if (tid < s2) red[tid] = fmaxf(red[tid], red[tid + s2]);
    __syncthreads();
  }
  float mz = red[0];
  __syncthreads();
  red[tid] = (tid < KK) ? __expf(v - mz) : 0.f;
  __syncthreads();
  for (int s2 = 256; s2 > 0; s2 >>= 1) {
    if (tid < s2) red[tid] += red[tid + s2];
    __syncthreads();
  }
  if (tid == 0) {
    float Z = mz + __logf(red[0]);
    int last_tag = y[b * 257 + len];
    out[b] = Z - (gold + tl[2][last_tag]);
  }
}

// ---------------------------------------------------------------------------
extern "C" void kernel_launch(void* const* d_in, const int* in_sizes, int n_in,
                              void* d_out, int out_size, void* d_ws, size_t ws_size,
                              hipStream_t stream) {
  const int*   cx    = (const int*)d_in[0];
  const int*   wx    = (const int*)d_in[1];
  const int*   y     = (const int*)d_in[2];
  const float* ce    = (const float*)d_in[3];
  const float* we    = (const float*)d_in[4];
  const float* Wi    = (const float*)d_in[5];
  const float* Wh    = (const float*)d_in[6];
  const float* bias  = (const float*)d_in[7];
  const float* Wout  = (const float*)d_in[8];
  const float* bout  = (const float*)d_in[9];
  const float* trans = (const float*)d_in[10];
  float* out = (float*)d_out;

  char* ws = (char*)d_ws;
  // ws layout (16B aligned), ~37 MB
  unsigned short* WcatT = (unsigned short*)(ws + 0);          // 3,145,728
  unsigned short* WoutT = (unsigned short*)(ws + 3145728);    //   131,072
  unsigned short* x     = (unsigned short*)(ws + 3276800);    // 8,388,608
  unsigned short* hs    = (unsigned short*)(ws + 11665408);   // 16,842,752
  unsigned int*   bar   = (unsigned int*)(ws + 28508160);     //         4
  float*          em    = (float*)(ws + 28639232);            // 8,388,608

  build_wcat<<<384, 256, 0, stream>>>(Wi, Wh, WcatT);
  build_wout<<<16, 256, 0, stream>>>(Wout, WoutT);
  embed_kernel<<<T_LEN * BB, 256, 0, stream>>>(wx, cx, we, ce, x);
  zero_bar<<<1, 1, 0, stream>>>(bar);
  lstm_persistent<<<NBLK, 512, 0, stream>>>(x, hs, WcatT, bias, wx, bar);
  em_gemm<<<256, 512, 0, stream>>>(hs, WoutT, bout, wx, em);
  crf_kernel<<<BB, 512, 0, stream>>>(em, trans, wx, y, out);
}

// Round 4
// 1847.470 us; speedup vs baseline: 2.6154x; 1.1745x over previous
//
#include <hip/hip_runtime.h>

// ---------------------------------------------------------------------------
// RNN (LSTM) + CRF loss on MI355X — round 4.
// LSTM: 32 persistent blocks x 256 thr (4 self-contained waves via
// operand-swapped MFMA: z^T = W^T h^T). Flag-vector barrier (per-block
// padded flag + one-vector-load poll), h exchange through LLC (sc0/sc1).
// ---------------------------------------------------------------------------

typedef float f32x4 __attribute__((ext_vector_type(4)));
typedef __bf16 bf16x8 __attribute__((ext_vector_type(8)));

#define T_LEN 256
#define BB    64
#define EE    256
#define HH    512
#define KK    128
#define KCAT  768   // E + H
#define NBLK  32

static __device__ inline unsigned short f2bf(float f) {
  union { float f; unsigned u; } v; v.f = f;
  unsigned r = v.u + 0x7FFF + ((v.u >> 16) & 1);   // round-nearest-even
  return (unsigned short)(r >> 16);
}
static __device__ inline float sigm(float x) { return 1.f / (1.f + __expf(-x)); }
static __device__ inline float tanh_fast(float x) {
  return 1.f - 2.f / (1.f + __expf(2.f * x));      // safe at +/-inf
}

// --- 1. weight conversion (LDS tile transpose, coalesced both sides) -------
__global__ __launch_bounds__(256) void build_wcat(
    const float* __restrict__ Wi, const float* __restrict__ Wh,
    unsigned short* __restrict__ WcatT) {
  __shared__ float tile[64][65];
  int ct = blockIdx.x & 31, kt = blockIdx.x >> 5;    // 32 c-tiles x 12 k-tiles
  int tc = threadIdx.x & 63, tr = threadIdx.x >> 6;
  int c0 = ct * 64, k0 = kt * 64;
#pragma unroll
  for (int i = 0; i < 16; ++i) {
    int r = tr * 16 + i, k = k0 + r;
    float v = (k < EE) ? Wi[(size_t)k * 2048 + c0 + tc]
                       : Wh[(size_t)(k - EE) * 2048 + c0 + tc];
    tile[r][tc] = v;
  }
  __syncthreads();
#pragma unroll
  for (int i = 0; i < 16; ++i) {
    int cL = tr * 16 + i;
    WcatT[(size_t)(c0 + cL) * KCAT + k0 + tc] = f2bf(tile[tc][cL]);
  }
}

__global__ __launch_bounds__(256) void build_wout(
    const float* __restrict__ Wout, unsigned short* __restrict__ WoutT) {
  __shared__ float tile[64][65];
  int ct = blockIdx.x & 1, kt = blockIdx.x >> 1;     // 2 c-tiles x 8 k-tiles
  int tc = threadIdx.x & 63, tr = threadIdx.x >> 6;
  int c0 = ct * 64, k0 = kt * 64;
#pragma unroll
  for (int i = 0; i < 16; ++i) {
    int r = tr * 16 + i;
    tile[r][tc] = Wout[(size_t)(k0 + r) * KK + c0 + tc];
  }
  __syncthreads();
#pragma unroll
  for (int i = 0; i < 16; ++i) {
    int cL = tr * 16 + i;
    WoutT[(size_t)(c0 + cL) * HH + k0 + tc] = f2bf(tile[tc][cL]);
  }
}

// --- 2. embedding ----------------------------------------------------------
__global__ __launch_bounds__(256) void embed_kernel(
    const int* __restrict__ wx, const int* __restrict__ cx,
    const float* __restrict__ we, const float* __restrict__ ce,
    unsigned short* __restrict__ x) {
  int bid = blockIdx.x;             // t*64 + b
  int t = bid >> 6, b = bid & 63;
  int e = threadIdx.x;              // 0..255
  int w = wx[b * T_LEN + t];
  float v = we[(size_t)w * EE + e];
  const int* cp = cx + ((size_t)(b * T_LEN + t)) * 8;
  float s = 0.f;
#pragma unroll
  for (int l = 0; l < 8; ++l) s += ce[(size_t)cp[l] * EE + e];
  v += s * 0.125f;
  x[(size_t)bid * EE + e] = f2bf(v);
}

// --- 3. flag reset ----------------------------------------------------------
__global__ void zero_flags(unsigned int* __restrict__ f) { f[threadIdx.x] = 0u; }

// --- 4. persistent LSTM ----------------------------------------------------
// Lane mapping (operand-swapped MFMA, D = Wfrag * Hfrag):
//   lane L of wave m: batch b = m*16 + (L&15); u rows = u0 + (L>>4)*4 + r.
//   acc[g][r] = z[b][gate g, u-row r]  -> all 4 gates in-lane, no LDS z.
__global__ __launch_bounds__(256, 1) void lstm_persistent(
    const unsigned short* __restrict__ x,     // [T][64][256] bf16
    unsigned short* __restrict__ hs,          // [T+1][64][512] bf16
    const unsigned short* __restrict__ WcatT, // [2048][768] bf16
    const float* __restrict__ bias,           // [2048]
    const int* __restrict__ wx,               // [64][256]
    unsigned int* __restrict__ flags) {       // 32 flags, 64B apart
  __shared__ unsigned short wlds[4 * 24 * 64 * 8];   // 96 KB, fragment order
  const int tid = threadIdx.x;
  const int u0 = blockIdx.x * 16;

  // stage weights in MFMA-fragment order:
  // frag(g,ks) lane L = WcatT[(g*512 + u0 + (L&15)) * 768 + ks*32 + (L>>4)*8]
  for (int i = tid; i < 4 * 24 * 64; i += 256) {
    int l = i & 63;
    int ks = (i >> 6) % 24;
    int g = i / (24 * 64);
    int gcol = g * HH + u0 + (l & 15);
    *(bf16x8*)(&wlds[(size_t)i * 8]) =
        *(const bf16x8*)(WcatT + (size_t)gcol * KCAT + ks * 32 + (l >> 4) * 8);
  }
  __syncthreads();

  const int wave = tid >> 6, lane = tid & 63;
  const int m = wave;                          // m-tile (16 batch rows)
  const int al = lane & 15, kg = (lane >> 4) * 8;
  const int b = m * 16 + al;                   // this lane's batch row
  const int urow = (lane >> 4) * 4;            // base u row within 16

  // per-gate LDS fragment bases (lane-fixed)
  const unsigned short* wg0 = wlds + ((size_t)(0 * 24) * 64 + lane) * 8;
  const unsigned short* wg1 = wlds + ((size_t)(1 * 24) * 64 + lane) * 8;
  const unsigned short* wg2 = wlds + ((size_t)(2 * 24) * 64 + lane) * 8;
  const unsigned short* wg3 = wlds + ((size_t)(3 * 24) * 64 + lane) * 8;

  float bv[4][4];
#pragma unroll
  for (int g = 0; g < 4; ++g)
#pragma unroll
    for (int r = 0; r < 4; ++r) bv[g][r] = bias[g * HH + u0 + urow + r];

  unsigned int* myflag = flags + (lane & 31) * 16;   // one flag per lane (x2)

  float cst[4] = {0.f, 0.f, 0.f, 0.f};
  float hst[4] = {0.f, 0.f, 0.f, 0.f};
  unsigned* hwp = (unsigned*)(hs + (size_t)BB * HH + (size_t)b * HH + u0 + urow);
  const unsigned short* xrow = x + (size_t)b * EE + kg;
  const unsigned short* hrow = hs + (size_t)b * HH + kg;

  for (int t = 0; t < T_LEN; ++t) {
    const int mk = wx[b * T_LEN + t];
    f32x4 acc0 = (f32x4){0.f,0.f,0.f,0.f}, acc1 = (f32x4){0.f,0.f,0.f,0.f};
    f32x4 acc2 = (f32x4){0.f,0.f,0.f,0.f}, acc3 = (f32x4){0.f,0.f,0.f,0.f};

    // x-part (h-independent; runs while other blocks finish step t-1)
    const unsigned short* xt = xrow + (size_t)t * BB * EE;
#pragma unroll
    for (int ks = 0; ks < 8; ++ks) {
      bf16x8 a = *(const bf16x8*)(xt + ks * 32);
      acc0 = __builtin_amdgcn_mfma_f32_16x16x32_bf16(*(const bf16x8*)(wg0 + ks * 512), a, acc0, 0, 0, 0);
      acc1 = __builtin_amdgcn_mfma_f32_16x16x32_bf16(*(const bf16x8*)(wg1 + ks * 512), a, acc1, 0, 0, 0);
      acc2 = __builtin_amdgcn_mfma_f32_16x16x32_bf16(*(const bf16x8*)(wg2 + ks * 512), a, acc2, 0, 0, 0);
      acc3 = __builtin_amdgcn_mfma_f32_16x16x32_bf16(*(const bf16x8*)(wg3 + ks * 512), a, acc3, 0, 0, 0);
    }
    __builtin_amdgcn_sched_barrier(0);

    if (t > 0) {
      // per-wave flag poll: one vector load checks all 32 producer flags
      unsigned v;
      do {
        asm volatile("global_load_dword %0, %1, off sc0 sc1\n\ts_waitcnt vmcnt(0)"
                     : "=v"(v) : "v"(myflag) : "memory");
      } while (!__all((int)(v >= (unsigned)t)));
      __builtin_amdgcn_sched_barrier(0);

      const unsigned short* hp = hrow + (size_t)t * BB * HH;
      bf16x8 hf[16];
#pragma unroll
      for (int ks = 0; ks < 16; ++ks)
        asm volatile("global_load_dwordx4 %0, %1, off sc0 sc1"
                     : "=v"(hf[ks]) : "v"(hp + ks * 32) : "memory");
      asm volatile("s_waitcnt vmcnt(0)" ::: "memory");
      __builtin_amdgcn_sched_barrier(0);
#pragma unroll
      for (int ks = 0; ks < 16; ++ks) {
        acc0 = __builtin_amdgcn_mfma_f32_16x16x32_bf16(*(const bf16x8*)(wg0 + (8 + ks) * 512), hf[ks], acc0, 0, 0, 0);
        acc1 = __builtin_amdgcn_mfma_f32_16x16x32_bf16(*(const bf16x8*)(wg1 + (8 + ks) * 512), hf[ks], acc1, 0, 0, 0);
        acc2 = __builtin_amdgcn_mfma_f32_16x16x32_bf16(*(const bf16x8*)(wg2 + (8 + ks) * 512), hf[ks], acc2, 0, 0, 0);
        acc3 = __builtin_amdgcn_mfma_f32_16x16x32_bf16(*(const bf16x8*)(wg3 + (8 + ks) * 512), hf[ks], acc3, 0, 0, 0);
      }
    }

    // gates, fully in-register (lane owns (b, u0+urow..+3))
#pragma unroll
    for (int r = 0; r < 4; ++r) {
      float zi = acc0[r] + bv[0][r];
      float zf = acc1[r] + bv[1][r];
      float zg = acc2[r] + bv[2][r];
      float zo = acc3[r] + bv[3][r];
      float cn = sigm(zf) * cst[r] + sigm(zi) * tanh_fast(zg);
      float hn = sigm(zo) * tanh_fast(cn);
      if (mk > 0) { cst[r] = cn; hst[r] = hn; }
    }
    unsigned pk0 = (unsigned)f2bf(hst[0]) | ((unsigned)f2bf(hst[1]) << 16);
    unsigned pk1 = (unsigned)f2bf(hst[2]) | ((unsigned)f2bf(hst[3]) << 16);
    unsigned* hw = hwp + (size_t)t * (BB * HH / 2);
    __hip_atomic_store(hw,     pk0, __ATOMIC_RELAXED, __HIP_MEMORY_SCOPE_AGENT);
    __hip_atomic_store(hw + 1, pk1, __ATOMIC_RELAXED, __HIP_MEMORY_SCOPE_AGENT);
    asm volatile("s_waitcnt vmcnt(0)" ::: "memory");   // h[t+1] ack'd at LLC
    __syncthreads();                                   // all waves drained
    if (tid == 0)
      __hip_atomic_store(flags + blockIdx.x * 16, (unsigned)(t + 1),
                         __ATOMIC_RELAXED, __HIP_MEMORY_SCOPE_AGENT);
  }
}

// --- 5. emissions GEMM: 256 blocks x 512 thr, 64 rows x 128 cols/block -----
__global__ __launch_bounds__(512) void em_gemm(
    const unsigned short* __restrict__ hs,    // A base = hs + 64*512
    const unsigned short* __restrict__ WoutT, // [128][512] bf16
    const float* __restrict__ bout,
    const int* __restrict__ wx,
    float* __restrict__ em) {                 // [16384][128]
  int mg = blockIdx.x;                        // 0..255
  int wave = threadIdx.x >> 6, lane = threadIdx.x & 63;
  int m = wave >> 1, nh = wave & 1;
  int arow = lane & 15, kg = (lane >> 4) * 8;
  int rbase = mg * 64 + m * 16;
  const unsigned short* A = hs + (size_t)BB * HH + (size_t)(rbase + arow) * HH + kg;
  f32x4 acc[4];
#pragma unroll
  for (int nt = 0; nt < 4; ++nt) acc[nt] = (f32x4){0.f, 0.f, 0.f, 0.f};
#pragma unroll
  for (int ks = 0; ks < 16; ++ks) {
    bf16x8 a = *(const bf16x8*)(A + ks * 32);
#pragma unroll
    for (int nt = 0; nt < 4; ++nt) {
      const unsigned short* Bp =
          WoutT + (size_t)(nh * 64 + nt * 16 + arow) * HH + kg + ks * 32;
      acc[nt] = __builtin_amdgcn_mfma_f32_16x16x32_bf16(a, *(const bf16x8*)Bp, acc[nt], 0, 0, 0);
    }
  }
#pragma unroll
  for (int nt = 0; nt < 4; ++nt) {
    int n = nh * 64 + nt * 16 + arow;
    float bo = bout[n];
#pragma unroll
    for (int r = 0; r < 4; ++r) {
      int row = rbase + (lane >> 4) * 4 + r;  // t*64 + b
      int t = row >> 6, b = row & 63;
      float v = (acc[nt][r] + bo) * ((wx[b * T_LEN + t] > 0) ? 1.f : 0.f);
      em[(size_t)row * KK + n] = v;
    }
  }
}

// --- 6. CRF forward + gold (512 threads: k x j-quarter) ---------------------
__global__ __launch_bounds__(512) void crf_kernel(
    const float* __restrict__ em,             // [256][64][128]
    const float* __restrict__ trans,          // [128][128]
    const int* __restrict__ wx,
    const int* __restrict__ y,                // [64][257]
    float* __restrict__ out) {
  int b = blockIdx.x;
  __shared__ float tl[KK][129];
  __shared__ float sc[KK];
  __shared__ float red[512];
  __shared__ float red2[512];
  int tid = threadIdx.x;
  for (int i = tid; i < KK * KK; i += 512) tl[i >> 7][i & 127] = trans[i];
  if (tid < KK) sc[tid] = (tid == 1) ? 0.f : -10000.f;
  __syncthreads();

  int k = tid & 127, q = tid >> 7, j0 = q * 32;

  for (int t = 0; t < T_LEN; ++t) {
    if (wx[b * T_LEN + t] <= 0) continue;     // block-uniform
    float mx = -1e30f;
#pragma unroll
    for (int j = 0; j < 32; ++j) mx = fmaxf(mx, sc[j0 + j] + tl[k][j0 + j]);
    float s = 0.f;
#pragma unroll
    for (int j = 0; j < 32; ++j) s += __expf(sc[j0 + j] + tl[k][j0 + j] - mx);
    red[tid] = mx; red2[tid] = s;
    __syncthreads();
    if (q == 0) {
      float M = mx, S = s;
#pragma unroll
      for (int qq = 1; qq < 4; ++qq) {
        float m2 = red[qq * 128 + k], s2 = red2[qq * 128 + k];
        float Mn = fmaxf(M, m2);
        S = S * __expf(M - Mn) + s2 * __expf(m2 - Mn);
        M = Mn;
      }
      sc[k] = em[(size_t)(t * BB + b) * KK + k] + M + __logf(S);
    }
    __syncthreads();
  }

  // gold score
  float term = 0.f, cnt = 0.f;
  if (tid < T_LEN) {
    int yp = y[b * 257 + tid], yn = y[b * 257 + tid + 1];
    if (wx[b * T_LEN + tid] > 0) {
      term = em[(size_t)(tid * BB + b) * KK + yn] + tl[yn][yp];
      cnt = 1.f;
    }
  }
  red[tid] = term; red2[tid] = cnt;
  __syncthreads();
  for (int s2 = 256; s2 > 0; s2 >>= 1) {
    if (tid < s2) { red[tid] += red[tid + s2]; red2[tid] += red2[tid + s2]; }
    __syncthreads();
  }
  float gold = red[0];
  int len = (int)(red2[0] + 0.5f);
  __syncthreads();

  // Z = LSE_k(sc[k] + trans[EOS][k])
  float v = (tid < KK) ? sc[tid] + tl[2][tid] : -3.0e38f;
  red[tid] = v;
  __syncthreads();
  for (int s2 = 256; s2 > 0; s2 >>= 1) {
    if (tid < s2) red[tid] = fmaxf(red[tid], red[tid + s2]);
    __syncthreads();
  }
  float mz = red[0];
  __syncthreads();
  red[tid] = (tid < KK) ? __expf(v - mz) : 0.f;
  __syncthreads();
  for (int s2 = 256; s2 > 0; s2 >>= 1) {
    if (tid < s2) red[tid] += red[tid + s2];
    __syncthreads();
  }
  if (tid == 0) {
    float Z = mz + __logf(red[0]);
    int last_tag = y[b * 257 + len];
    out[b] = Z - (gold + tl[2][last_tag]);
  }
}

// ---------------------------------------------------------------------------
extern "C" void kernel_launch(void* const* d_in, const int* in_sizes, int n_in,
                              void* d_out, int out_size, void* d_ws, size_t ws_size,
                              hipStream_t stream) {
  const int*   cx    = (const int*)d_in[0];
  const int*   wx    = (const int*)d_in[1];
  const int*   y     = (const int*)d_in[2];
  const float* ce    = (const float*)d_in[3];
  const float* we    = (const float*)d_in[4];
  const float* Wi    = (const float*)d_in[5];
  const float* Wh    = (const float*)d_in[6];
  const float* bias  = (const float*)d_in[7];
  const float* Wout  = (const float*)d_in[8];
  const float* bout  = (const float*)d_in[9];
  const float* trans = (const float*)d_in[10];
  float* out = (float*)d_out;

  char* ws = (char*)d_ws;
  // ws layout (16B aligned), ~37 MB
  unsigned short* WcatT = (unsigned short*)(ws + 0);          // 3,145,728
  unsigned short* WoutT = (unsigned short*)(ws + 3145728);    //   131,072
  unsigned short* x     = (unsigned short*)(ws + 3276800);    // 8,388,608
  unsigned short* hs    = (unsigned short*)(ws + 11665408);   // 16,842,752
  unsigned int*   flags = (unsigned int*)(ws + 28508160);     //     2,048
  float*          em    = (float*)(ws + 28639232);            // 8,388,608

  build_wcat<<<384, 256, 0, stream>>>(Wi, Wh, WcatT);
  build_wout<<<16, 256, 0, stream>>>(Wout, WoutT);
  embed_kernel<<<T_LEN * BB, 256, 0, stream>>>(wx, cx, we, ce, x);
  zero_flags<<<1, 512, 0, stream>>>(flags);
  lstm_persistent<<<NBLK, 256, 0, stream>>>(x, hs, WcatT, bias, wx, flags);
  em_gemm<<<256, 512, 0, stream>>>(hs, WoutT, bout, wx, em);
  crf_kernel<<<BB, 512, 0, stream>>>(em, trans, wx, y, out);
}

// Round 6
// 1757.148 us; speedup vs baseline: 2.7498x; 1.0514x over previous
//
#include <hip/hip_runtime.h>

// ---------------------------------------------------------------------------
// RNN (LSTM) + CRF loss on MI355X — round 6.
// LSTM: 64 persistent blocks x 128 thr, 32x32x16 swapped MFMA (lane owns one
// batch x 4 u x all 4 gates -> gates in registers), all 48 weight fragments
// register-resident (192 VGPR), zero LDS. h exchange = round-4's PROVEN
// protocol: sc0/sc1 h store -> vmcnt ack -> syncthreads -> per-block flag;
// consumers poll 64 packed flags (1 coalesced dword/lane) then sc0/sc1-load h.
// ---------------------------------------------------------------------------

typedef float f32x4 __attribute__((ext_vector_type(4)));
typedef float f32x16 __attribute__((ext_vector_type(16)));
typedef __bf16 bf16x8 __attribute__((ext_vector_type(8)));
typedef unsigned int u32x4 __attribute__((ext_vector_type(4)));
typedef unsigned int u32x2 __attribute__((ext_vector_type(2)));

#define T_LEN 256
#define BB    64
#define EE    256
#define HH    512
#define KK    128
#define KCAT  768   // E + H

static __device__ inline unsigned f2bf(float f) {
  union { float f; unsigned u; } v; v.f = f;
  unsigned r = v.u + 0x7FFF + ((v.u >> 16) & 1);   // round-nearest-even
  return r >> 16;
}
static __device__ inline float sigm(float x) { return 1.f / (1.f + __expf(-x)); }
static __device__ inline float tanh_fast(float x) {
  return 1.f - 2.f / (1.f + __expf(2.f * x));      // safe at +/-inf
}
static __device__ inline bf16x8 ubf(u32x4 v) {
  union { u32x4 u; bf16x8 b; } c; c.u = v; return c.b;
}

// --- 1. weight conversion (LDS tile transpose, coalesced both sides) -------
__global__ __launch_bounds__(256) void build_wcat(
    const float* __restrict__ Wi, const float* __restrict__ Wh,
    unsigned short* __restrict__ WcatT) {
  __shared__ float tile[64][65];
  int ct = blockIdx.x & 31, kt = blockIdx.x >> 5;    // 32 c-tiles x 12 k-tiles
  int tc = threadIdx.x & 63, tr = threadIdx.x >> 6;
  int c0 = ct * 64, k0 = kt * 64;
#pragma unroll
  for (int i = 0; i < 16; ++i) {
    int r = tr * 16 + i, k = k0 + r;
    float v = (k < EE) ? Wi[(size_t)k * 2048 + c0 + tc]
                       : Wh[(size_t)(k - EE) * 2048 + c0 + tc];
    tile[r][tc] = v;
  }
  __syncthreads();
#pragma unroll
  for (int i = 0; i < 16; ++i) {
    int cL = tr * 16 + i;
    WcatT[(size_t)(c0 + cL) * KCAT + k0 + tc] = (unsigned short)f2bf(tile[tc][cL]);
  }
}

__global__ __launch_bounds__(256) void build_wout(
    const float* __restrict__ Wout, unsigned short* __restrict__ WoutT) {
  __shared__ float tile[64][65];
  int ct = blockIdx.x & 1, kt = blockIdx.x >> 1;     // 2 c-tiles x 8 k-tiles
  int tc = threadIdx.x & 63, tr = threadIdx.x >> 6;
  int c0 = ct * 64, k0 = kt * 64;
#pragma unroll
  for (int i = 0; i < 16; ++i) {
    int r = tr * 16 + i;
    tile[r][tc] = Wout[(size_t)(k0 + r) * KK + c0 + tc];
  }
  __syncthreads();
#pragma unroll
  for (int i = 0; i < 16; ++i) {
    int cL = tr * 16 + i;
    WoutT[(size_t)(c0 + cL) * HH + k0 + tc] = (unsigned short)f2bf(tile[tc][cL]);
  }
}

// --- 2. embedding ----------------------------------------------------------
__global__ __launch_bounds__(256) void embed_kernel(
    const int* __restrict__ wx, const int* __restrict__ cx,
    const float* __restrict__ we, const float* __restrict__ ce,
    unsigned short* __restrict__ x) {
  int bid = blockIdx.x;             // t*64 + b
  int t = bid >> 6, b = bid & 63;
  int e = threadIdx.x;              // 0..255
  int w = wx[b * T_LEN + t];
  float v = we[(size_t)w * EE + e];
  const int* cp = cx + ((size_t)(b * T_LEN + t)) * 8;
  float s = 0.f;
#pragma unroll
  for (int l = 0; l < 8; ++l) s += ce[(size_t)cp[l] * EE + e];
  v += s * 0.125f;
  x[(size_t)bid * EE + e] = (unsigned short)f2bf(v);
}

// --- 3. flag reset (sc0 sc1 so LLC-bypass poll loads see the zeros) --------
__global__ void zero_flags(unsigned int* __restrict__ f) {
  unsigned z = 0u;
  asm volatile("global_store_dword %0, %1, off sc0 sc1"
               :: "v"(f + threadIdx.x), "v"(z) : "memory");
}

// --- 4. persistent LSTM ----------------------------------------------------
#define SBAR __builtin_amdgcn_sched_barrier(0)
#define WAITV(N) do { asm volatile("s_waitcnt vmcnt(" #N ")" ::: "memory"); SBAR; } while (0)
#define LDC(dst, ptr, OFF) \
  asm volatile("global_load_dwordx4 %0, %1, off offset:" OFF " sc0 sc1" \
               : "=v"(dst) : "v"(ptr) : "memory")
#define LDN(dst, ptr, OFF) \
  asm volatile("global_load_dwordx4 %0, %1, off offset:" OFF \
               : "=v"(dst) : "v"(ptr) : "memory")

#define ISSUE_X(B, P) do { \
  LDN(B[0],P,"0");   LDN(B[1],P,"32");  LDN(B[2],P,"64");  LDN(B[3],P,"96"); \
  LDN(B[4],P,"128"); LDN(B[5],P,"160"); LDN(B[6],P,"192"); LDN(B[7],P,"224"); \
  LDN(B[8],P,"256"); LDN(B[9],P,"288"); LDN(B[10],P,"320"); LDN(B[11],P,"352"); \
  LDN(B[12],P,"384"); LDN(B[13],P,"416"); LDN(B[14],P,"448"); LDN(B[15],P,"480"); } while (0)
#define ISSUE_H0(B, P) do { \
  LDC(B[0],P,"0");   LDC(B[1],P,"32");  LDC(B[2],P,"64");  LDC(B[3],P,"96"); \
  LDC(B[4],P,"128"); LDC(B[5],P,"160"); LDC(B[6],P,"192"); LDC(B[7],P,"224"); \
  LDC(B[8],P,"256"); LDC(B[9],P,"288"); LDC(B[10],P,"320"); LDC(B[11],P,"352"); \
  LDC(B[12],P,"384"); LDC(B[13],P,"416"); LDC(B[14],P,"448"); LDC(B[15],P,"480"); } while (0)
#define ISSUE_H1(B, P) do { \
  LDC(B[0],P,"512"); LDC(B[1],P,"544"); LDC(B[2],P,"576"); LDC(B[3],P,"608"); \
  LDC(B[4],P,"640"); LDC(B[5],P,"672"); LDC(B[6],P,"704"); LDC(B[7],P,"736"); \
  LDC(B[8],P,"768"); LDC(B[9],P,"800"); LDC(B[10],P,"832"); LDC(B[11],P,"864"); \
  LDC(B[12],P,"896"); LDC(B[13],P,"928"); LDC(B[14],P,"960"); LDC(B[15],P,"992"); } while (0)

#define GATES_STORE(T) do { \
    bool mk = ((int)wxv) > 0; \
    _Pragma("unroll") \
    for (int r = 0; r < 4; ++r) { \
      float zi = acc[r], zf = acc[4 + r], zg = acc[8 + r], zo = acc[12 + r]; \
      float cn = sigm(zf) * cst[r] + sigm(zi) * tanh_fast(zg); \
      float hn = sigm(zo) * tanh_fast(cn); \
      if (mk) { cst[r] = cn; hst[r] = hn; } \
    } \
    u32x2 ph; \
    ph[0] = f2bf(hst[0]) | (f2bf(hst[1]) << 16); \
    ph[1] = f2bf(hst[2]) | (f2bf(hst[3]) << 16); \
    asm volatile("global_store_dwordx2 %0, %1, off sc0 sc1" \
                 :: "v"(hstore + (size_t)(T) * 65536), "v"(ph) : "memory"); \
  } while (0)

// wave = 32 batches x 32 z-cols (32x32x16 swapped MFMA, D = Wfrag x Hfrag).
// D: col = lane&31 (batch), row = (reg&3) + 8*(reg>>2) + 4*(lane>>5)
//    = gate*8 + uoff  -> acc[g*4+r] = gate g, u = u0 + 4*hi + r. All 4 gates
// in-lane; weight A-frags (rows = z-cols) loop-invariant in 192 VGPRs.
__global__ __launch_bounds__(128, 1) void lstm_persistent(
    const unsigned short* __restrict__ x,      // [T][64][256] bf16
    unsigned short* __restrict__ hs,           // [256][64][512] bf16 (slot t = h[t+1])
    const unsigned short* __restrict__ WcatT,  // [2048][768] bf16
    const float* __restrict__ bias,            // [2048]
    const int* __restrict__ wx,                // [64][256]
    unsigned int* __restrict__ flags) {        // 64 packed dwords
  const int tid = threadIdx.x;
  const int lane = tid & 63;
  const int bhalf = tid >> 6;                  // 2 waves: batch halves
  const int hi = lane >> 5;
  const int batch = bhalf * 32 + (lane & 31);
  const int u0 = blockIdx.x * 8;               // block's u-slice [u0, u0+8)
  const int rr = lane & 31;                    // A-frag row = z-col id
  const int wcol = (rr >> 3) * HH + u0 + (rr & 7);   // gate*512 + u0 + uoff

  // 48 loop-invariant weight A-frags -> 192 VGPRs
  bf16x8 wreg[48];
#pragma unroll
  for (int kf = 0; kf < 48; ++kf)
    wreg[kf] = *(const bf16x8*)(WcatT + (size_t)wcol * KCAT + kf * 16 + hi * 8);

  float bv[16];
#pragma unroll
  for (int q = 0; q < 4; ++q)
#pragma unroll
    for (int r = 0; r < 4; ++r)
      bv[q * 4 + r] = bias[q * HH + u0 + 4 * hi + r];

  const char* xlane  = (const char*)x  + ((size_t)batch * EE + hi * 8) * 2;
  const char* hread  = (const char*)hs + ((size_t)batch * HH + hi * 8) * 2;
  char*       hstore = (char*)hs + ((size_t)batch * HH + u0 + 4 * hi) * 2;
  const int*  wxp    = wx + batch * T_LEN;

  float cst[4] = {0.f, 0.f, 0.f, 0.f};
  float hst[4] = {0.f, 0.f, 0.f, 0.f};
  u32x4 bufX[16], bufH[16];
  unsigned wxv;
  f32x16 acc;

  // ---- t = 0 (h = 0: x-part only) ----
  ISSUE_X(bufX, xlane);
  asm volatile("global_load_dword %0, %1, off" : "=v"(wxv) : "v"(wxp) : "memory");
  WAITV(0);
#pragma unroll
  for (int i = 0; i < 16; ++i) acc[i] = bv[i];
#pragma unroll
  for (int kf = 0; kf < 16; ++kf)
    acc = __builtin_amdgcn_mfma_f32_32x32x16_bf16(wreg[kf], ubf(bufX[kf]), acc, 0, 0, 0);
  GATES_STORE(0);
  WAITV(0);                                    // h[1] ack'd at LLC
  __syncthreads();
  if (tid == 0)
    __hip_atomic_store(flags + blockIdx.x, 1u, __ATOMIC_RELAXED, __HIP_MEMORY_SCOPE_AGENT);

  // ---- t = 1..255 ----
  for (int t = 1; t < T_LEN; ++t) {
    const char* xt = xlane + (size_t)t * 32768;
    const char* hp = hread + (size_t)(t - 1) * 65536;

    ISSUE_X(bufX, xt);
    asm volatile("global_load_dword %0, %1, off" : "=v"(wxv) : "v"(wxp + t) : "memory");
    // poll 64 packed producer flags: one coalesced dword per lane
    {
      unsigned v;
      do {
        asm volatile("global_load_dword %0, %1, off sc0 sc1\n\ts_waitcnt vmcnt(0)"
                     : "=v"(v) : "v"(flags + lane) : "memory");
      } while (!__all((int)(v >= (unsigned)t)));
      SBAR;
    }
    ISSUE_H0(bufH, hp);                        // h chunk 0 in flight
#pragma unroll
    for (int i = 0; i < 16; ++i) acc[i] = bv[i];
#pragma unroll
    for (int kf = 0; kf < 16; ++kf)            // x-part (data arrived: poll drained)
      acc = __builtin_amdgcn_mfma_f32_32x32x16_bf16(wreg[kf], ubf(bufX[kf]), acc, 0, 0, 0);
    SBAR;
    ISSUE_H1(bufX, hp);                        // h chunk 1 reuses x buffer
    WAITV(16);                                 // chunk 0 arrived
#pragma unroll
    for (int kf = 0; kf < 16; ++kf)
      acc = __builtin_amdgcn_mfma_f32_32x32x16_bf16(wreg[16 + kf], ubf(bufH[kf]), acc, 0, 0, 0);
    WAITV(0);                                  // chunk 1 arrived
#pragma unroll
    for (int kf = 0; kf < 16; ++kf)
      acc = __builtin_amdgcn_mfma_f32_32x32x16_bf16(wreg[32 + kf], ubf(bufX[kf]), acc, 0, 0, 0);
    GATES_STORE(t);
    WAITV(0);                                  // h[t+1] ack'd at LLC
    __syncthreads();                           // both waves drained
    if (tid == 0)
      __hip_atomic_store(flags + blockIdx.x, (unsigned)(t + 1),
                         __ATOMIC_RELAXED, __HIP_MEMORY_SCOPE_AGENT);
  }
}

// --- 5. emissions GEMM: 256 blocks x 512 thr, 64 rows x 128 cols/block -----
__global__ __launch_bounds__(512) void em_gemm(
    const unsigned short* __restrict__ hs,    // [256][64][512] bf16
    const unsigned short* __restrict__ WoutT, // [128][512] bf16
    const float* __restrict__ bout,
    const int* __restrict__ wx,
    float* __restrict__ em) {                 // [16384][128]
  int mg = blockIdx.x;                        // 0..255
  int wave = threadIdx.x >> 6, lane = threadIdx.x & 63;
  int m = wave >> 1, nh = wave & 1;
  int arow = lane & 15, kg = (lane >> 4) * 8;
  int rbase = mg * 64 + m * 16;
  const unsigned short* A = hs + (size_t)(rbase + arow) * HH + kg;
  f32x4 acc[4];
#pragma unroll
  for (int nt = 0; nt < 4; ++nt) acc[nt] = (f32x4){0.f, 0.f, 0.f, 0.f};
#pragma unroll
  for (int ks = 0; ks < 16; ++ks) {
    bf16x8 a = *(const bf16x8*)(A + ks * 32);
#pragma unroll
    for (int nt = 0; nt < 4; ++nt) {
      const unsigned short* Bp =
          WoutT + (size_t)(nh * 64 + nt * 16 + arow) * HH + kg + ks * 32;
      acc[nt] = __builtin_amdgcn_mfma_f32_16x16x32_bf16(a, *(const bf16x8*)Bp, acc[nt], 0, 0, 0);
    }
  }
#pragma unroll
  for (int nt = 0; nt < 4; ++nt) {
    int n = nh * 64 + nt * 16 + arow;
    float bo = bout[n];
#pragma unroll
    for (int r = 0; r < 4; ++r) {
      int row = rbase + (lane >> 4) * 4 + r;  // t*64 + b
      int t = row >> 6, b = row & 63;
      float v = (acc[nt][r] + bo) * ((wx[b * T_LEN + t] > 0) ? 1.f : 0.f);
      em[(size_t)row * KK + n] = v;
    }
  }
}

// --- 6. CRF forward + gold (512 threads: k x j-quarter) ---------------------
__global__ __launch_bounds__(512) void crf_kernel(
    const float* __restrict__ em,             // [256][64][128]
    const float* __restrict__ trans,          // [128][128]
    const int* __restrict__ wx,
    const int* __restrict__ y,                // [64][257]
    float* __restrict__ out) {
  int b = blockIdx.x;
  __shared__ float tl[KK][129];
  __shared__ float sc[KK];
  __shared__ float red[512];
  __shared__ float red2[512];
  int tid = threadIdx.x;
  for (int i = tid; i < KK * KK; i += 512) tl[i >> 7][i & 127] = trans[i];
  if (tid < KK) sc[tid] = (tid == 1) ? 0.f : -10000.f;
  __syncthreads();

  int k = tid & 127, q = tid >> 7, j0 = q * 32;

  for (int t = 0; t < T_LEN; ++t) {
    if (wx[b * T_LEN + t] <= 0) continue;     // block-uniform
    float mx = -1e30f;
#pragma unroll
    for (int j = 0; j < 32; ++j) mx = fmaxf(mx, sc[j0 + j] + tl[k][j0 + j]);
    float s = 0.f;
#pragma unroll
    for (int j = 0; j < 32; ++j) s += __expf(sc[j0 + j] + tl[k][j0 + j] - mx);
    red[tid] = mx; red2[tid] = s;
    __syncthreads();
    if (q == 0) {
      float M = mx, S = s;
#pragma unroll
      for (int qq = 1; qq < 4; ++qq) {
        float m2 = red[qq * 128 + k], s2 = red2[qq * 128 + k];
        float Mn = fmaxf(M, m2);
        S = S * __expf(M - Mn) + s2 * __expf(m2 - Mn);
        M = Mn;
      }
      sc[k] = em[(size_t)(t * BB + b) * KK + k] + M + __logf(S);
    }
    __syncthreads();
  }

  // gold score
  float term = 0.f, cnt = 0.f;
  if (tid < T_LEN) {
    int yp = y[b * 257 + tid], yn = y[b * 257 + tid + 1];
    if (wx[b * T_LEN + tid] > 0) {
      term = em[(size_t)(tid * BB + b) * KK + yn] + tl[yn][yp];
      cnt = 1.f;
    }
  }
  red[tid] = term; red2[tid] = cnt;
  __syncthreads();
  for (int s2 = 256; s2 > 0; s2 >>= 1) {
    if (tid < s2) { red[tid] += red[tid + s2]; red2[tid] += red2[tid + s2]; }
    __syncthreads();
  }
  float gold = red[0];
  int len = (int)(red2[0] + 0.5f);
  __syncthreads();

  // Z = LSE_k(sc[k] + trans[EOS][k])
  float v = (tid < KK) ? sc[tid] + tl[2][tid] : -3.0e38f;
  red[tid] = v;
  __syncthreads();
  for (int s2 = 256; s2 > 0; s2 >>= 1) {
    if (tid < s2) red[tid] = fmaxf(red[tid], red[tid + s2]);
    __syncthreads();
  }
  float mz = red[0];
  __syncthreads();
  red[tid] = (tid < KK) ? __expf(v - mz) : 0.f;
  __syncthreads();
  for (int s2 = 256; s2 > 0; s2 >>= 1) {
    if (tid < s2) red[tid] += red[tid + s2];
    __syncthreads();
  }
  if (tid == 0) {
    float Z = mz + __logf(red[0]);
    int last_tag = y[b * 257 + len];
    out[b] = Z - (gold + tl[2][last_tag]);
  }
}

// ---------------------------------------------------------------------------
extern "C" void kernel_launch(void* const* d_in, const int* in_sizes, int n_in,
                              void* d_out, int out_size, void* d_ws, size_t ws_size,
                              hipStream_t stream) {
  const int*   cx    = (const int*)d_in[0];
  const int*   wx    = (const int*)d_in[1];
  const int*   y     = (const int*)d_in[2];
  const float* ce    = (const float*)d_in[3];
  const float* we    = (const float*)d_in[4];
  const float* Wi    = (const float*)d_in[5];
  const float* Wh    = (const float*)d_in[6];
  const float* bias  = (const float*)d_in[7];
  const float* Wout  = (const float*)d_in[8];
  const float* bout  = (const float*)d_in[9];
  const float* trans = (const float*)d_in[10];
  float* out = (float*)d_out;

  char* ws = (char*)d_ws;
  // ws layout (16B aligned), ~28.5 MB; em aliases x (x dead after lstm)
  unsigned short* WcatT = (unsigned short*)(ws + 0);          //  3,145,728
  unsigned short* WoutT = (unsigned short*)(ws + 3145728);    //    131,072
  unsigned short* x     = (unsigned short*)(ws + 3276800);    //  8,388,608
  unsigned short* hs    = (unsigned short*)(ws + 11665408);   // 16,777,216
  unsigned int*   flags = (unsigned int*)(ws + 28442624);     //        256
  float*          em    = (float*)(ws + 3276800);             //  8,388,608 (alias x)

  build_wcat<<<384, 256, 0, stream>>>(Wi, Wh, WcatT);
  build_wout<<<16, 256, 0, stream>>>(Wout, WoutT);
  embed_kernel<<<T_LEN * BB, 256, 0, stream>>>(wx, cx, we, ce, x);
  zero_flags<<<1, 64, 0, stream>>>(flags);
  lstm_persistent<<<64, 128, 0, stream>>>(x, hs, WcatT, bias, wx, flags);
  em_gemm<<<256, 512, 0, stream>>>(hs, WoutT, bout, wx, em);
  crf_kernel<<<BB, 512, 0, stream>>>(em, trans, wx, y, out);
}